// Round 12
// baseline (51.434 us; speedup 1.0000x reference)
//
#include <hip/hip_runtime.h>

// NNLoss: min over 5x5 shifted neighborhoods of channel-summed L1 distance,
// then global mean. B=16, C=3, H=W=512, fp32.
// R12: full-width bands (512x8 per block) -> gt reads are contiguous 40 KB
// ranges per channel (no horizontal halo); vertical halo shared on-XCD via
// bijective chunked swizzle. LDS [3][12][524] = 75.5 KB, 2 blocks/CU.
// Two-half gather-then-write staging (reg-light). Fused tail: last block
// (atomic counter, memset to 0 per launch) reduces partials in fixed order.

#define PADV (-10000.0f)

constexpr int Bn = 16, Cn = 3, Hn = 512, Wn = 512;
constexpr long PLANE = (long)Hn * Wn;                  // 262144

constexpr int TH = 8;
constexpr int GH = TH + 4;                             // 12 rows: h0-2..h0+9
constexpr int F4ROW = 131;                             // float4: cols -4..519
constexpr int GW = 4 * F4ROW;                          // 524 (== 12 mod 32)
constexpr int BLOCK = 512;
constexpr int F4T = Cn * GH * F4ROW;                   // 4716
constexpr int NBANDS = Hn / TH;                        // 64
constexpr int NBLOCKS = Bn * NBANDS;                   // 1024

__global__ __launch_bounds__(BLOCK, 2) void nnloss_fused(
    const float* __restrict__ pred, const float* __restrict__ gt,
    float* __restrict__ out, float* __restrict__ ws) {
  unsigned int* cnt = (unsigned int*)ws;
  volatile float* partial = ws + 64;

  // bijective chunked XCD swizzle: xcd = blockIdx.x%8 owns 128 consecutive
  // wg's -> vertically adjacent bands co-located for halo L2 reuse.
  const int wg = ((blockIdx.x & 7) << 7) | (blockIdx.x >> 3);
  const int band = wg & (NBANDS - 1);
  const int b = wg >> 6;
  const int h0 = band * TH;

  __shared__ __align__(16) float tile[Cn][GH][GW];     // 75,456 B

  const float* gb = gt + (long)b * Cn * PLANE;
  const float* pb = pred + (long)b * Cn * PLANE;

  const int tid = threadIdx.x;
  const int ty = tid & 7;                              // output row in band
  const int tx = tid >> 3;                             // 64 strips of 8 px

  // ---- pred: 8 px/thread, issued early (consumed after barrier) ----
  float p[Cn][8];
  {
    const float* pp = pb + (long)(h0 + ty) * Wn + 8 * tx;
#pragma unroll
    for (int c = 0; c < Cn; ++c) {
      const float4 v0 = *(const float4*)(pp + (long)c * PLANE);
      const float4 v1 = *(const float4*)(pp + (long)c * PLANE + 4);
      p[c][0] = v0.x; p[c][1] = v0.y; p[c][2] = v0.z; p[c][3] = v0.w;
      p[c][4] = v1.x; p[c][5] = v1.y; p[c][6] = v1.z; p[c][7] = v1.w;
    }
  }

  // ---- stage gt: fully sequential runs; two gather-then-write halves ----
#pragma unroll
  for (int half = 0; half < 2; ++half) {
    float4 sv[5];
#pragma unroll
    for (int m = 0; m < 5; ++m) {
      const int idx = tid + (half * 5 + m) * BLOCK;
      if (idx < F4T) {
        const int c = idx / (GH * F4ROW);
        const int rem = idx - c * (GH * F4ROW);
        const int r = rem / F4ROW;
        const int k = rem - r * F4ROW;
        const int ghc = min(max(h0 - 2 + r, 0), Hn - 1);
        const int gcc = min(max(4 * k - 4, 0), Wn - 4);
        sv[m] = *(const float4*)(gb + (long)c * PLANE + (long)ghc * Wn + gcc);
      }
    }
#pragma unroll
    for (int m = 0; m < 5; ++m) {
      const int idx = tid + (half * 5 + m) * BLOCK;
      if (idx < F4T) {
        const int c = idx / (GH * F4ROW);
        const int rem = idx - c * (GH * F4ROW);
        const int r = rem / F4ROW;
        const int k = rem - r * F4ROW;
        const int gh = h0 - 2 + r;
        const int gc0 = 4 * k - 4;
        const bool rb = (gh < 0) || (gh >= Hn);
        float4 v = sv[m];
        v.x = (rb || gc0 + 0 < 0 || gc0 + 0 >= Wn) ? PADV : v.x;
        v.y = (rb || gc0 + 1 < 0 || gc0 + 1 >= Wn) ? PADV : v.y;
        v.z = (rb || gc0 + 2 < 0 || gc0 + 2 >= Wn) ? PADV : v.z;
        v.w = (rb || gc0 + 3 < 0 || gc0 + 3 >= Wn) ? PADV : v.w;
        *(float4*)&tile[c][r][4 * k] = v;
      }
    }
  }
  __syncthreads();

  // ---- compute: window cols L = 8tx+2 .. 8tx+13 (g[q+dj+2]) ----
  float m8[8];
#pragma unroll
  for (int q = 0; q < 8; ++q) m8[q] = 3.0e38f;

#pragma unroll
  for (int di = 0; di < 5; ++di) {
    float s[5][8];
    float g[14];
#pragma unroll
    for (int c = 0; c < Cn; ++c) {
      const float* base = &tile[c][ty + di][8 * tx];
      const float2 e0 = *(const float2*)(base + 2);
      const float4 A = *(const float4*)(base + 4);
      const float4 B2 = *(const float4*)(base + 8);
      const float2 e1 = *(const float2*)(base + 12);
      g[2] = e0.x;  g[3] = e0.y;
      g[4] = A.x;   g[5] = A.y;   g[6] = A.z;   g[7] = A.w;
      g[8] = B2.x;  g[9] = B2.y;  g[10] = B2.z; g[11] = B2.w;
      g[12] = e1.x; g[13] = e1.y;
      if (c == 0) {
#pragma unroll
        for (int dj = 0; dj < 5; ++dj)
#pragma unroll
          for (int q = 0; q < 8; ++q)
            s[dj][q] = fabsf(g[q + dj + 2] - p[0][q]);
      } else {
#pragma unroll
        for (int dj = 0; dj < 5; ++dj)
#pragma unroll
          for (int q = 0; q < 8; ++q)
            s[dj][q] += fabsf(g[q + dj + 2] - p[c][q]);
      }
    }
#pragma unroll
    for (int q = 0; q < 8; ++q) {
      const float t1 = fminf(fminf(s[0][q], s[1][q]), s[2][q]);   // v_min3
      const float t2 = fminf(fminf(t1, s[3][q]), s[4][q]);        // v_min3
      m8[q] = fminf(m8[q], t2);
    }
  }

  float v = ((m8[0] + m8[1]) + (m8[2] + m8[3])) +
            ((m8[4] + m8[5]) + (m8[6] + m8[7]));

  // ---- block reduction ----
#pragma unroll
  for (int off = 32; off > 0; off >>= 1) v += __shfl_down(v, off, 64);
  __shared__ float wsum[BLOCK / 64];
  __shared__ bool slast;
  const int lane = tid & 63;
  const int wid = tid >> 6;
  if (lane == 0) wsum[wid] = v;
  __syncthreads();
  if (tid == 0) {
    float tsum = 0.f;
#pragma unroll
    for (int i = 0; i < BLOCK / 64; ++i) tsum += wsum[i];
    partial[wg] = tsum;
    __threadfence();                                   // publish partial
    const unsigned o = atomicAdd(cnt, 1u);             // device-scope
    slast = (o == (unsigned)(NBLOCKS - 1));
  }
  __syncthreads();

  // ---- fused tail: last block reduces all partials, fixed order ----
  if (slast) {
    __threadfence();                                   // acquire
    double acc = (double)partial[tid] + (double)partial[tid + BLOCK];
#pragma unroll
    for (int off = 32; off > 0; off >>= 1) acc += __shfl_down(acc, off, 64);
    __shared__ double sd[BLOCK / 64];
    if (lane == 0) sd[wid] = acc;
    __syncthreads();
    if (tid == 0) {
      double tot = 0.0;
#pragma unroll
      for (int i = 0; i < BLOCK / 64; ++i) tot += sd[i];
      out[0] = (float)(tot / ((double)Bn * Hn * Wn));
    }
  }
}

extern "C" void kernel_launch(void* const* d_in, const int* in_sizes, int n_in,
                              void* d_out, int out_size, void* d_ws, size_t ws_size,
                              hipStream_t stream) {
  const float* pred = (const float*)d_in[0];
  const float* gt = (const float*)d_in[1];
  // d_in[2], d_in[3] are nh=5, nw=5 (hard-coded)
  float* out = (float*)d_out;
  float* ws = (float*)d_ws;  // [0..63]: counter+pad, [64..64+1024): partials

  hipMemsetAsync(d_ws, 0, 256, stream);                // zero the counter
  nnloss_fused<<<NBLOCKS, BLOCK, 0, stream>>>(pred, gt, out, ws);
}